// Round 7
// baseline (212.847 us; speedup 1.0000x reference)
//
#include <hip/hip_runtime.h>
#include <hip/hip_bf16.h>

#define HH   512
#define BB   8192
#define WIDTH (1.0f/16.0f)

typedef __attribute__((ext_vector_type(8)))  short short8;    // 8 bf16 = 4 VGPRs
typedef __attribute__((ext_vector_type(4)))  float floatx4;
typedef __attribute__((ext_vector_type(16))) float floatx16;

typedef const __attribute__((address_space(1))) void* gptr_t;
typedef __attribute__((address_space(3))) void*       lptr_t;

__device__ __forceinline__ void gload_lds16(const void* g, void* l) {
    // async global->LDS, 16B per lane; LDS dst = wave-uniform base + lane*16
    __builtin_amdgcn_global_load_lds((gptr_t)g, (lptr_t)l, 16, 0, 0);
}

__device__ __forceinline__ float tanh_fast(float x) {
    float e = __expf(2.0f * x);
    return 1.0f - 2.0f * __builtin_amdgcn_rcpf(e + 1.0f);
}

// ---- prep_all: W2 transpose | W1 transpose | prep_v, one dispatch ----
__global__ void prep_all(const float* __restrict__ vin, const float* __restrict__ W1,
                         const float* __restrict__ W2,
                         float* __restrict__ vout,
                         __hip_bfloat16* __restrict__ Abf,
                         __hip_bfloat16* __restrict__ W1T,
                         __hip_bfloat16* __restrict__ W2T) {
    __shared__ float tile[32][33];
    int bid = blockIdx.x, tid = threadIdx.x;
    if (bid < 4352) {
        // transpose branch: W2 (512x8192) for bid<4096, else W1 (512x512)
        const float* src;  __hip_bfloat16* dst;  int cols, c0, r0;
        if (bid < 4096) { src = W2; dst = W2T; cols = 8192; c0 = (bid & 255) * 32; r0 = (bid >> 8) * 32; }
        else            { int b = bid - 4096; src = W1; dst = W1T; cols = 512; c0 = (b & 15) * 32; r0 = (b >> 4) * 32; }
        int x = tid & 31, y = tid >> 5;            // (32,8) logical
        #pragma unroll
        for (int i = 0; i < 32; i += 8)
            tile[y + i][x] = src[(size_t)(r0 + y + i) * cols + c0 + x];
        __syncthreads();
        #pragma unroll
        for (int i = 0; i < 32; i += 8)
            dst[(size_t)(c0 + y + i) * 512 + r0 + x] = __float2bfloat16(tile[x][y + i]);
    } else {
        // prep_v branch: v_out[:, :512] = v_in[:, :512]; Abf = bf16(v_p - 0.5)
        int b = bid - 4352;                        // 0..2047
        int i = b * 256 + tid;                     // group-of-8 index
        int r = i >> 6, c = i & 63;
        const float4* src = (const float4*)(vin + (size_t)r * 1024 + c * 8);
        float4 f0 = src[0], f1 = src[1];
        float4* dst = (float4*)(vout + (size_t)r * 1024 + c * 8);
        dst[0] = f0; dst[1] = f1;
        union { __hip_bfloat16 h[8]; uint4 v; } u;
        u.h[0] = __float2bfloat16(f0.x - 0.5f); u.h[1] = __float2bfloat16(f0.y - 0.5f);
        u.h[2] = __float2bfloat16(f0.z - 0.5f); u.h[3] = __float2bfloat16(f0.w - 0.5f);
        u.h[4] = __float2bfloat16(f1.x - 0.5f); u.h[5] = __float2bfloat16(f1.y - 0.5f);
        u.h[6] = __float2bfloat16(f1.z - 0.5f); u.h[7] = __float2bfloat16(f1.w - 0.5f);
        *(uint4*)(Abf + (size_t)r * 512 + c * 8) = u.v;
    }
}

// ------- GEMM1: h = tanh(Abf @ W1T^T + b1), 64x128 tiles, 512 blocks (2/CU) -------
__global__ __launch_bounds__(256, 4) void gemm1_kernel(
        const __hip_bfloat16* __restrict__ Abf,   // (8192,512) bf16, = v_p - 0.5
        const __hip_bfloat16* __restrict__ W1T,   // (512,512) [n][k] bf16
        const float* __restrict__ b1,
        __hip_bfloat16* __restrict__ hM) {        // (8192,512) bf16
    __shared__ short ldsA[64 * 32];               // 4 KB
    __shared__ short ldsB[128 * 32];              // 8 KB
    int tid = threadIdx.x;
    int lane = tid & 63;
    int wv = tid >> 6, wr = wv >> 1, wc = wv & 1;
    int q = lane >> 4, cx = lane & 15;
    int rowBase = blockIdx.y * 64;
    int colBase = blockIdx.x * 128;
    floatx4 acc[2][4] = {};

    for (int k0 = 0; k0 < HH; k0 += 32) {
        {   // A tile: 64 rows x 32 k = 256 chunks, 1 per thread
            int row = tid >> 2, kc = tid & 3;
            unsigned loff = __builtin_amdgcn_readfirstlane((unsigned)((tid & 192) * 16));
            gload_lds16(Abf + (size_t)(rowBase + row) * HH + k0 + kc * 8, (char*)ldsA + loff);
        }
        #pragma unroll
        for (int j = 0; j < 2; ++j) {   // B tile: 128 x 32 = 512 chunks
            int i = j * 256 + tid;
            int row = i >> 2, kc = i & 3;
            unsigned loff = __builtin_amdgcn_readfirstlane((unsigned)((j * 256 + (tid & 192)) * 16));
            gload_lds16(W1T + (size_t)(colBase + row) * HH + k0 + kc * 8, (char*)ldsB + loff);
        }
        __syncthreads();
        short8 a[2], b[4];
        #pragma unroll
        for (int mt = 0; mt < 2; ++mt)
            a[mt] = *(const short8*)(ldsA + (wr * 32 + mt * 16 + cx) * 32 + q * 8);
        #pragma unroll
        for (int nt = 0; nt < 4; ++nt)
            b[nt] = *(const short8*)(ldsB + (wc * 64 + nt * 16 + cx) * 32 + q * 8);
        #pragma unroll
        for (int mt = 0; mt < 2; ++mt)
            #pragma unroll
            for (int nt = 0; nt < 4; ++nt)
                acc[mt][nt] = __builtin_amdgcn_mfma_f32_16x16x32_bf16(a[mt], b[nt], acc[mt][nt], 0, 0, 0);
        __syncthreads();
    }

    float b1v[4];
    #pragma unroll
    for (int nt = 0; nt < 4; ++nt) b1v[nt] = b1[colBase + wc * 64 + nt * 16 + cx];
    #pragma unroll
    for (int mt = 0; mt < 2; ++mt)
        #pragma unroll
        for (int nt = 0; nt < 4; ++nt) {
            int col = colBase + wc * 64 + nt * 16 + cx;
            #pragma unroll
            for (int r = 0; r < 4; ++r) {
                int row = rowBase + wr * 32 + mt * 16 + q * 4 + r;  // C: col=lane&15, row=quad*4+reg
                hM[(size_t)row * HH + col] = __float2bfloat16(tanh_fast(acc[mt][nt][r] + b1v[nt]));
            }
        }
}

// ------- GEMM2 fused: net=tanh(h@W2+b2); softmax(16); spline; log-partials -------
// 32x32x16 MFMA (17% less MFMA-pipe time vs 16x16x32 — m119). BK=64 as two 32k halves.
// Chunk-placement swizzle slot=c^(row&3): fragment reads 16-way -> 8-way conflicts.
__global__ __launch_bounds__(256, 4) void gemm2_kernel(
        const __hip_bfloat16* __restrict__ hM,    // (8192,512) bf16
        const __hip_bfloat16* __restrict__ W2T,   // (8192,512) [n][k] bf16
        const float* __restrict__ b2,             // (8192) fp32
        const float* __restrict__ vin,            // (8192,1024) fp32, active cols 512..1023
        float* __restrict__ vout,                 // (8192,1024) fp32
        float* __restrict__ partial) {            // (8192,128) fp32
    __shared__ __align__(16) char smem[34816];    // stage: A 16K + B 16K; epi: 4w x 32x68 f32
    short* ldsA = (short*)smem;
    short* ldsB = (short*)(smem + 16384);
    float* ldsE = (float*)smem;
    int tid = threadIdx.x;
    int lane = tid & 63;
    int wv = tid >> 6, wr = wv >> 1, wc = wv & 1;
    int m31 = lane & 31, q2 = lane >> 5;          // 32x32 fragment coords
    int rowBase = blockIdx.y * 128;
    int colBase = blockIdx.x * 128;
    floatx16 acc[2][2] = {};

    int key = (lane & 3);                         // swizzle key = fragment row & 3

    for (int k0 = 0; k0 < HH; k0 += 64) {
        #pragma unroll
        for (int j = 0; j < 4; ++j) {             // 1024 chunks per matrix: two 32k halves
            int chunk = j * 256 + tid;
            int half  = j >> 1;
            int c2    = chunk & 511;
            int row = c2 >> 2, slot = c2 & 3;
            int kcs = slot ^ (row & 3);           // slot holds source chunk slot^(row&3)
            unsigned loff = __builtin_amdgcn_readfirstlane((unsigned)((j * 256 + (tid & 192)) * 16));
            gload_lds16(hM  + (size_t)(rowBase + row) * HH + k0 + half * 32 + kcs * 8, (char*)ldsA + loff);
            gload_lds16(W2T + (size_t)(colBase + row) * HH + k0 + half * 32 + kcs * 8, (char*)ldsB + loff);
        }
        __syncthreads();
        #pragma unroll
        for (int h = 0; h < 2; ++h) {             // 32k half
            const short* pA = ldsA + h * 4096;
            const short* pB = ldsB + h * 4096;
            #pragma unroll
            for (int s = 0; s < 2; ++s) {         // K=16 sub-step
                int slot = (s * 2 + q2) ^ key;    // swizzled chunk slot for this lane
                short8 a[2], b[2];
                #pragma unroll
                for (int mt = 0; mt < 2; ++mt)
                    a[mt] = *(const short8*)(pA + (wr * 64 + mt * 32 + m31) * 32 + slot * 8);
                #pragma unroll
                for (int nt = 0; nt < 2; ++nt)
                    b[nt] = *(const short8*)(pB + (wc * 64 + nt * 32 + m31) * 32 + slot * 8);
                #pragma unroll
                for (int mt = 0; mt < 2; ++mt)
                    #pragma unroll
                    for (int nt = 0; nt < 2; ++nt)
                        acc[mt][nt] = __builtin_amdgcn_mfma_f32_32x32x16_bf16(a[mt], b[nt], acc[mt][nt], 0, 0, 0);
            }
        }
        __syncthreads();   // staging LDS dead after last iter -> epilogue may reuse
    }

    float b2v[2];
    #pragma unroll
    for (int nt = 0; nt < 2; ++nt) b2v[nt] = b2[colBase + wc * 64 + nt * 32 + m31];

    float* myTile = ldsE + wv * (32 * 68);        // wave-private 32x68: no barrier needed

    #pragma unroll
    for (int mt = 0; mt < 2; ++mt) {
        // write phase: 32x64 slab in 32x32 C-layout (col=lane&31, row=(reg&3)+8(reg>>2)+4q2)
        #pragma unroll
        for (int nt = 0; nt < 2; ++nt)
            #pragma unroll
            for (int reg = 0; reg < 16; ++reg) {
                int r = (reg & 3) + 8 * (reg >> 2) + 4 * q2;
                myTile[r * 68 + nt * 32 + m31] = acc[mt][nt][reg] + b2v[nt];
            }
        // no __syncthreads: tile is wave-private; compiler inserts lgkmcnt wait

        float lpsum = 0.0f;
        #pragma unroll
        for (int gi = 0; gi < 2; ++gi) {          // lane handles 2 (row,group) pairs
            int g = q2 * 2 + gi;                  // group within wave's 64 cols
            floatx4 x0 = *(const floatx4*)(myTile + m31 * 68 + g * 16);
            floatx4 x1 = *(const floatx4*)(myTile + m31 * 68 + g * 16 + 4);
            floatx4 x2 = *(const floatx4*)(myTile + m31 * 68 + g * 16 + 8);
            floatx4 x3 = *(const floatx4*)(myTile + m31 * 68 + g * 16 + 12);
            float xs[16] = { x0[0],x0[1],x0[2],x0[3], x1[0],x1[1],x1[2],x1[3],
                             x2[0],x2[1],x2[2],x2[3], x3[0],x3[1],x3[2],x3[3] };

            int row  = rowBase + wr * 64 + mt * 32 + m31;
            int gAbs = blockIdx.x * 8 + wc * 4 + g;
            float v = vin[(size_t)row * 1024 + 512 + gAbs];
            int k = (int)ceilf(v * 16.0f) - 1;    // exact searchsorted('left')-1 (v*16 exact)
            k = min(15, max(0, k));

            float s = 0.0f, csum = 0.0f, ek = 0.0f;
            #pragma unroll
            for (int j = 0; j < 16; ++j) {
                float e2 = __expf(2.0f * xs[j]);
                float t  = 1.0f - 2.0f * __builtin_amdgcn_rcpf(e2 + 1.0f);   // tanh
                float e  = __expf(t);             // t in [-1,1]: no max-subtract needed
                csum += (j < k)  ? e : 0.0f;
                ek    = (j == k) ? e : ek;
                s += e;
            }
            float rs = __builtin_amdgcn_rcpf(s);
            float pk  = ek * rs;
            float ylo = csum * rs;
            float alpha = (v - (float)k * WIDTH) * 16.0f;
            vout[(size_t)row * 1024 + 512 + gAbs] = ylo + alpha * pk;
            lpsum += __logf(pk);
        }
        int row = rowBase + wr * 64 + mt * 32 + m31;
        lpsum += __shfl_xor(lpsum, 32, 64);       // combine the two q2 group-pairs per row
        if (lane < 32) partial[(size_t)row * 128 + blockIdx.x * 2 + wc] = lpsum;
    }
}

// ---------------- final: ld_out[b] = ld[b] - sum_{cb} partial[b][cb] ----------------
__global__ void finish_logdens(const float* __restrict__ partial,
                               const float* __restrict__ ld,
                               float* __restrict__ out) {
    int wv = threadIdx.x >> 6, lane = threadIdx.x & 63;
    int row = blockIdx.x * 4 + wv;
    float s = partial[(size_t)row * 128 + lane] + partial[(size_t)row * 128 + 64 + lane];
    #pragma unroll
    for (int d = 32; d > 0; d >>= 1) s += __shfl_down(s, d, 64);
    if (lane == 0) out[row] = ld[row] - s;
}

extern "C" void kernel_launch(void* const* d_in, const int* in_sizes, int n_in,
                              void* d_out, int out_size, void* d_ws, size_t ws_size,
                              hipStream_t stream) {
    const float* vin = (const float*)d_in[0];
    const float* ld  = (const float*)d_in[1];
    const float* W1  = (const float*)d_in[2];
    const float* b1  = (const float*)d_in[3];
    const float* W2  = (const float*)d_in[4];
    const float* b2  = (const float*)d_in[5];
    float* vout  = (float*)d_out;
    float* ldout = vout + (size_t)BB * 1024;

    char* ws = (char*)d_ws;                                    // layout (16B aligned):
    __hip_bfloat16* Abf = (__hip_bfloat16*)(ws);               //  8 MB  @ 0
    __hip_bfloat16* W1T = (__hip_bfloat16*)(ws + 8388608);     //  0.5MB
    __hip_bfloat16* W2T = (__hip_bfloat16*)(ws + 8912896);     //  8 MB
    __hip_bfloat16* hM  = (__hip_bfloat16*)(ws + 17301504);    //  8 MB
    float* partial = (float*)(ws + 25690112);                  //  4 MB  (total ~29.7MB)

    prep_all<<<6400, 256, 0, stream>>>(vin, W1, W2, vout, Abf, W1T, W2T);
    gemm1_kernel<<<dim3(4, 128), 256, 0, stream>>>(Abf, W1T, b1, hM);
    gemm2_kernel<<<dim3(64, 64), 256, 0, stream>>>(hM, W2T, b2, vin, vout, partial);
    finish_logdens<<<2048, 256, 0, stream>>>(partial, ld, ldout);
}

// Round 8
// 201.631 us; speedup vs baseline: 1.0556x; 1.0556x over previous
//
#include <hip/hip_runtime.h>
#include <hip/hip_bf16.h>

#define HH   512
#define BB   8192
#define WIDTH (1.0f/16.0f)

typedef __attribute__((ext_vector_type(8))) short  short8;   // 8 bf16 = 4 VGPRs
typedef __attribute__((ext_vector_type(4))) float  floatx4;

typedef const __attribute__((address_space(1))) void* gptr_t;
typedef __attribute__((address_space(3))) void*       lptr_t;

__device__ __forceinline__ void gload_lds16(const void* g, void* l) {
    // async global->LDS, 16B per lane; LDS dst = wave-uniform base + lane*16
    __builtin_amdgcn_global_load_lds((gptr_t)g, (lptr_t)l, 16, 0, 0);
}

__device__ __forceinline__ float tanh_fast(float x) {
    float e = __expf(2.0f * x);
    return 1.0f - 2.0f * __builtin_amdgcn_rcpf(e + 1.0f);
}

// ---- prep_all: W2 transpose | W1 transpose | prep_v + ldout init, one dispatch ----
__global__ void prep_all(const float* __restrict__ vin, const float* __restrict__ W1,
                         const float* __restrict__ W2, const float* __restrict__ ld,
                         float* __restrict__ vout, float* __restrict__ ldout,
                         __hip_bfloat16* __restrict__ Abf,
                         __hip_bfloat16* __restrict__ W1T,
                         __hip_bfloat16* __restrict__ W2T) {
    __shared__ float tile[32][33];
    int bid = blockIdx.x, tid = threadIdx.x;
    if (bid < 4352) {
        // transpose branch: W2 (512x8192) for bid<4096, else W1 (512x512)
        const float* src;  __hip_bfloat16* dst;  int cols, c0, r0;
        if (bid < 4096) { src = W2; dst = W2T; cols = 8192; c0 = (bid & 255) * 32; r0 = (bid >> 8) * 32; }
        else            { int b = bid - 4096; src = W1; dst = W1T; cols = 512; c0 = (b & 15) * 32; r0 = (b >> 4) * 32; }
        int x = tid & 31, y = tid >> 5;            // (32,8) logical
        #pragma unroll
        for (int i = 0; i < 32; i += 8)
            tile[y + i][x] = src[(size_t)(r0 + y + i) * cols + c0 + x];
        __syncthreads();
        #pragma unroll
        for (int i = 0; i < 32; i += 8)
            dst[(size_t)(c0 + y + i) * 512 + r0 + x] = __float2bfloat16(tile[x][y + i]);
    } else {
        // prep_v branch: v_out[:, :512] = v_in[:, :512]; Abf = bf16(v_p - 0.5); ldout = ld
        int b = bid - 4352;                        // 0..2047
        int i = b * 256 + tid;                     // group-of-8 index
        int r = i >> 6, c = i & 63;
        const float4* src = (const float4*)(vin + (size_t)r * 1024 + c * 8);
        float4 f0 = src[0], f1 = src[1];
        float4* dst = (float4*)(vout + (size_t)r * 1024 + c * 8);
        dst[0] = f0; dst[1] = f1;
        union { __hip_bfloat16 h[8]; uint4 v; } u;
        u.h[0] = __float2bfloat16(f0.x - 0.5f); u.h[1] = __float2bfloat16(f0.y - 0.5f);
        u.h[2] = __float2bfloat16(f0.z - 0.5f); u.h[3] = __float2bfloat16(f0.w - 0.5f);
        u.h[4] = __float2bfloat16(f1.x - 0.5f); u.h[5] = __float2bfloat16(f1.y - 0.5f);
        u.h[6] = __float2bfloat16(f1.z - 0.5f); u.h[7] = __float2bfloat16(f1.w - 0.5f);
        *(uint4*)(Abf + (size_t)r * 512 + c * 8) = u.v;
        if (tid < 4) { int row = b * 4 + tid; ldout[row] = ld[row]; }
    }
}

// ------- GEMM1: h = tanh(Abf @ W1T^T + b1), 64x128 tiles, 512 blocks (2/CU) -------
__global__ __launch_bounds__(256, 4) void gemm1_kernel(
        const __hip_bfloat16* __restrict__ Abf,   // (8192,512) bf16, = v_p - 0.5
        const __hip_bfloat16* __restrict__ W1T,   // (512,512) [n][k] bf16
        const float* __restrict__ b1,
        __hip_bfloat16* __restrict__ hM) {        // (8192,512) bf16
    __shared__ short ldsA[64 * 32];               // 4 KB
    __shared__ short ldsB[128 * 32];              // 8 KB
    int tid = threadIdx.x;
    int lane = tid & 63;
    int wv = tid >> 6, wr = wv >> 1, wc = wv & 1;
    int q = lane >> 4, cx = lane & 15;
    int rowBase = blockIdx.y * 64;
    int colBase = blockIdx.x * 128;
    floatx4 acc[2][4] = {};

    for (int k0 = 0; k0 < HH; k0 += 32) {
        {   // A tile: 64 rows x 32 k = 256 chunks, 1 per thread
            int row = tid >> 2, kc = tid & 3;
            unsigned loff = __builtin_amdgcn_readfirstlane((unsigned)((tid & 192) * 16));
            gload_lds16(Abf + (size_t)(rowBase + row) * HH + k0 + kc * 8, (char*)ldsA + loff);
        }
        #pragma unroll
        for (int j = 0; j < 2; ++j) {   // B tile: 128 x 32 = 512 chunks
            int i = j * 256 + tid;
            int row = i >> 2, kc = i & 3;
            unsigned loff = __builtin_amdgcn_readfirstlane((unsigned)((j * 256 + (tid & 192)) * 16));
            gload_lds16(W1T + (size_t)(colBase + row) * HH + k0 + kc * 8, (char*)ldsB + loff);
        }
        __syncthreads();
        short8 a[2], b[4];
        #pragma unroll
        for (int mt = 0; mt < 2; ++mt)
            a[mt] = *(const short8*)(ldsA + (wr * 32 + mt * 16 + cx) * 32 + q * 8);
        #pragma unroll
        for (int nt = 0; nt < 4; ++nt)
            b[nt] = *(const short8*)(ldsB + (wc * 64 + nt * 16 + cx) * 32 + q * 8);
        #pragma unroll
        for (int mt = 0; mt < 2; ++mt)
            #pragma unroll
            for (int nt = 0; nt < 4; ++nt)
                acc[mt][nt] = __builtin_amdgcn_mfma_f32_16x16x32_bf16(a[mt], b[nt], acc[mt][nt], 0, 0, 0);
        __syncthreads();
    }

    float b1v[4];
    #pragma unroll
    for (int nt = 0; nt < 4; ++nt) b1v[nt] = b1[colBase + wc * 64 + nt * 16 + cx];
    #pragma unroll
    for (int mt = 0; mt < 2; ++mt)
        #pragma unroll
        for (int nt = 0; nt < 4; ++nt) {
            int col = colBase + wc * 64 + nt * 16 + cx;
            #pragma unroll
            for (int r = 0; r < 4; ++r) {
                int row = rowBase + wr * 32 + mt * 16 + q * 4 + r;  // C: col=lane&15, row=quad*4+reg
                hM[(size_t)row * HH + col] = __float2bfloat16(tanh_fast(acc[mt][nt][r] + b1v[nt]));
            }
        }
}

// ------- GEMM2 fused: net=tanh(h@W2+b2); softmax(16); spline; atomic log-dens -------
// 16x16x32 MFMA, BK=64 (two stacked BK=32 tiles). XCD y-panel swizzle: bid&7 picks a
// 1024-row hM panel (1 MB -> fits 4 MB per-XCD L2); ldout atomics become XCD-local.
__global__ __launch_bounds__(256, 4) void gemm2_kernel(
        const __hip_bfloat16* __restrict__ hM,    // (8192,512) bf16
        const __hip_bfloat16* __restrict__ W2T,   // (8192,512) [n][k] bf16
        const float* __restrict__ b2,             // (8192) fp32
        const float* __restrict__ vin,            // (8192,1024) fp32, active cols 512..1023
        float* __restrict__ vout,                 // (8192,1024) fp32
        float* __restrict__ ldout) {              // (8192) fp32, pre-initialized to ld
    __shared__ __align__(16) char smem[32768];    // A: 16K (2 halves), B: 16K; epilogue reuses
    short* ldsA = (short*)smem;
    short* ldsB = (short*)(smem + 16384);
    float* ldsE = (float*)smem;                   // epilogue: 4 waves x 16x68 fp32 (17408 B)
    int tid = threadIdx.x;
    int lane = tid & 63;
    int wv = tid >> 6, wr = wv >> 1, wc = wv & 1;
    int q = lane >> 4, cx = lane & 15;
    // XCD swizzle: round-robin dispatch puts bid&7 on XCD (bid&7); give each XCD a
    // contiguous 8-block y-panel and iterate x within it.
    int bid = blockIdx.x;                         // 0..4095
    int xcd = bid & 7, w = bid >> 3;
    int by  = xcd * 8 + (w & 7);                  // y panel: 1024 rows per XCD
    int bx  = w >> 3;                             // 0..63
    int rowBase = by * 128;
    int colBase = bx * 128;
    floatx4 acc[4][4] = {};

    for (int k0 = 0; k0 < HH; k0 += 64) {
        #pragma unroll
        for (int j = 0; j < 4; ++j) {             // 1024 chunks per matrix: two BK=32 tiles
            int chunk = j * 256 + tid;
            int half  = j >> 1;
            int c2    = chunk & 511;
            int row = c2 >> 2, kc = c2 & 3;
            unsigned loff = __builtin_amdgcn_readfirstlane((unsigned)((j * 256 + (tid & 192)) * 16));
            gload_lds16(hM  + (size_t)(rowBase + row) * HH + k0 + half * 32 + kc * 8, (char*)ldsA + loff);
            gload_lds16(W2T + (size_t)(colBase + row) * HH + k0 + half * 32 + kc * 8, (char*)ldsB + loff);
        }
        __syncthreads();
        #pragma unroll
        for (int s = 0; s < 2; ++s) {             // sub-step: +8KB immediate offset
            const short* pA = ldsA + s * 4096;
            const short* pB = ldsB + s * 4096;
            short8 a[4], b[4];
            #pragma unroll
            for (int mt = 0; mt < 4; ++mt)
                a[mt] = *(const short8*)(pA + (wr * 64 + mt * 16 + cx) * 32 + q * 8);
            #pragma unroll
            for (int nt = 0; nt < 4; ++nt)
                b[nt] = *(const short8*)(pB + (wc * 64 + nt * 16 + cx) * 32 + q * 8);
            #pragma unroll
            for (int mt = 0; mt < 4; ++mt)
                #pragma unroll
                for (int nt = 0; nt < 4; ++nt)
                    acc[mt][nt] = __builtin_amdgcn_mfma_f32_16x16x32_bf16(a[mt], b[nt], acc[mt][nt], 0, 0, 0);
        }
        __syncthreads();   // staging LDS dead after last iter -> epilogue may reuse
    }

    float b2v[4];
    #pragma unroll
    for (int nt = 0; nt < 4; ++nt) b2v[nt] = b2[colBase + wc * 64 + nt * 16 + cx];

    float* myTile = ldsE + wv * (16 * 68);        // wave-private: no barrier needed
    int rowL  = lane & 15;                         // read-phase: lane's row within 16-row slab
    int gL    = lane >> 4;                         // lane's group (0..3) within wave's 64 cols
    int gAbs  = bx * 8 + wc * 4 + gL;             // absolute h-group index

    #pragma unroll
    for (int mt = 0; mt < 4; ++mt) {
        // write phase: C-layout slab (16 rows x 64 cols) -> LDS, +b2 folded in
        #pragma unroll
        for (int nt = 0; nt < 4; ++nt)
            #pragma unroll
            for (int r = 0; r < 4; ++r)
                myTile[(q * 4 + r) * 68 + nt * 16 + cx] = acc[mt][nt][r] + b2v[nt];
        // no __syncthreads: tile is wave-private; compiler inserts lgkmcnt wait

        // read phase: lane owns (row=rowL, group=gL): 16 contiguous floats
        floatx4 x0 = *(const floatx4*)(myTile + rowL * 68 + gL * 16);
        floatx4 x1 = *(const floatx4*)(myTile + rowL * 68 + gL * 16 + 4);
        floatx4 x2 = *(const floatx4*)(myTile + rowL * 68 + gL * 16 + 8);
        floatx4 x3 = *(const floatx4*)(myTile + rowL * 68 + gL * 16 + 12);
        float xs[16] = { x0[0],x0[1],x0[2],x0[3], x1[0],x1[1],x1[2],x1[3],
                         x2[0],x2[1],x2[2],x2[3], x3[0],x3[1],x3[2],x3[3] };

        int row = rowBase + wr * 64 + mt * 16 + rowL;
        float v = vin[(size_t)row * 1024 + 512 + gAbs];
        int k = (int)ceilf(v * 16.0f) - 1;        // exact searchsorted('left')-1 (v*16 exact)
        k = min(15, max(0, k));

        float s = 0.0f, csum = 0.0f, ek = 0.0f;
        #pragma unroll
        for (int j = 0; j < 16; ++j) {
            float e2 = __expf(2.0f * xs[j]);
            float t  = 1.0f - 2.0f * __builtin_amdgcn_rcpf(e2 + 1.0f);   // tanh
            float e  = __expf(t);                 // t in [-1,1]: no max-subtract needed
            csum += (j < k)  ? e : 0.0f;
            ek    = (j == k) ? e : ek;
            s += e;
        }
        float rs = __builtin_amdgcn_rcpf(s);
        float pk  = ek * rs;
        float ylo = csum * rs;
        float alpha = (v - (float)k * WIDTH) * 16.0f;
        vout[(size_t)row * 1024 + 512 + gAbs] = ylo + alpha * pk;

        float logp = __logf(pk);
        logp += __shfl_xor(logp, 16, 64);          // reduce over 4 groups sharing a row
        logp += __shfl_xor(logp, 32, 64);
        if (lane < 16) atomicAdd(ldout + row, -logp);   // XCD-local: row in this XCD's panel
    }
}

extern "C" void kernel_launch(void* const* d_in, const int* in_sizes, int n_in,
                              void* d_out, int out_size, void* d_ws, size_t ws_size,
                              hipStream_t stream) {
    const float* vin = (const float*)d_in[0];
    const float* ld  = (const float*)d_in[1];
    const float* W1  = (const float*)d_in[2];
    const float* b1  = (const float*)d_in[3];
    const float* W2  = (const float*)d_in[4];
    const float* b2  = (const float*)d_in[5];
    float* vout  = (float*)d_out;
    float* ldout = vout + (size_t)BB * 1024;

    char* ws = (char*)d_ws;                                    // layout (16B aligned):
    __hip_bfloat16* Abf = (__hip_bfloat16*)(ws);               //  8 MB  @ 0
    __hip_bfloat16* W1T = (__hip_bfloat16*)(ws + 8388608);     //  0.5MB
    __hip_bfloat16* W2T = (__hip_bfloat16*)(ws + 8912896);     //  8 MB
    __hip_bfloat16* hM  = (__hip_bfloat16*)(ws + 17301504);    //  8 MB  (total ~24.5MB)

    prep_all<<<6400, 256, 0, stream>>>(vin, W1, W2, ld, vout, ldout, Abf, W1T, W2T);
    gemm1_kernel<<<dim3(4, 128), 256, 0, stream>>>(Abf, W1T, b1, hM);
    gemm2_kernel<<<4096, 256, 0, stream>>>(hM, W2T, b2, vin, vout, ldout);
}